// Round 1
// baseline (1030.414 us; speedup 1.0000x reference)
//
#include <hip/hip_runtime.h>
#include <math.h>

// Problem constants
// B=4, NQ=256, DQ=256, DKV=256, H_IMG=W_IMG=256, HEADS=8, DH=32,
// TOPW=4, WS=8, FACTOR=2, INNER=256, DOUT=256
// conv out spatial: 128x128 -> M=N=16 windows of 64 dilated tokens.
// x layout: [bwin(1024)][t(64)][c(256)], bwin = b*256 + m*16 + n, t = h*8+w,
// pixel (y,x) = (h*16+m, w*16+n).

// ---------------- K1: conv patchify as implicit GEMM ----------------
__global__ __launch_bounds__(256) void k_conv(
    const float* __restrict__ img, const float* __restrict__ cw,
    const float* __restrict__ cb, float* __restrict__ x)
{
  __shared__ float As[32][132];   // k-major: As[kk][pp], pp = column 0..127
  __shared__ float Bs[32][260];   // Bs[kk][o], o = 0..255
  const int tid = threadIdx.x;
  const int blk = blockIdx.x;            // 512 = 4 batches * 128 rows
  const int b = blk >> 7, y = blk & 127;
  const int ty = tid >> 4, tx = tid & 15;

  float acc[8][16];
#pragma unroll
  for (int i = 0; i < 8; ++i)
#pragma unroll
    for (int j = 0; j < 16; ++j) acc[i][j] = 0.f;

  const int pp = tid & 127, rr = tid >> 7;
  const float* ibase = img + (size_t)b * 16777216 + (size_t)(2 * y) * 256 + 2 * pp;
  const int g = tid & 7, oo = tid >> 3;

  for (int kc = 0; kc < 32; ++kc) {
    // A stage: 8 cin x (2 ky x 2 kx) patch elems for 128 spatial columns
#pragma unroll
    for (int u = 0; u < 8; ++u) {
      const int pair = rr * 8 + u;          // 0..15
      const int ci = pair >> 1, ky = pair & 1;
      const int cin = kc * 8 + ci;
      const float2 v = *(const float2*)(ibase + (size_t)cin * 65536 + ky * 256);
      As[ci * 4 + ky * 2 + 0][pp] = v.x;
      As[ci * 4 + ky * 2 + 1][pp] = v.y;
    }
    // B stage: conv_w rows are already (cin,ky,kx)-flat
#pragma unroll
    for (int rep = 0; rep < 8; ++rep) {
      const int o = rep * 32 + oo;
      const float4 v = *(const float4*)(cw + (size_t)o * 1024 + kc * 32 + g * 4);
      Bs[g * 4 + 0][o] = v.x; Bs[g * 4 + 1][o] = v.y;
      Bs[g * 4 + 2][o] = v.z; Bs[g * 4 + 3][o] = v.w;
    }
    __syncthreads();
#pragma unroll
    for (int kk = 0; kk < 32; ++kk) {
      float a[8];
      const float4 a0 = *(const float4*)&As[kk][ty * 8];
      const float4 a1 = *(const float4*)&As[kk][ty * 8 + 4];
      a[0] = a0.x; a[1] = a0.y; a[2] = a0.z; a[3] = a0.w;
      a[4] = a1.x; a[5] = a1.y; a[6] = a1.z; a[7] = a1.w;
      float4 bv[4];
#pragma unroll
      for (int jj = 0; jj < 4; ++jj) bv[jj] = *(const float4*)&Bs[kk][tx * 4 + jj * 64];
#pragma unroll
      for (int i = 0; i < 8; ++i)
#pragma unroll
        for (int jj = 0; jj < 4; ++jj) {
          acc[i][jj * 4 + 0] += a[i] * bv[jj].x;
          acc[i][jj * 4 + 1] += a[i] * bv[jj].y;
          acc[i][jj * 4 + 2] += a[i] * bv[jj].z;
          acc[i][jj * 4 + 3] += a[i] * bv[jj].w;
        }
    }
    __syncthreads();
  }
  // epilogue: + bias, scatter into dilated-window layout
  const int hh = y >> 4, m = y & 15;
#pragma unroll
  for (int i = 0; i < 8; ++i) {
    const int p = ty * 8 + i;
    const int w = p >> 4, n = p & 15;
    const int bwin = b * 256 + m * 16 + n;
    const int t = hh * 8 + w;
    float* dst = x + ((size_t)(bwin * 64 + t)) * 256 + tx * 4;
#pragma unroll
    for (int jj = 0; jj < 4; ++jj) {
      float4 v;
      v.x = acc[i][jj * 4 + 0] + cb[tx * 4 + jj * 64 + 0];
      v.y = acc[i][jj * 4 + 1] + cb[tx * 4 + jj * 64 + 1];
      v.z = acc[i][jj * 4 + 2] + cb[tx * 4 + jj * 64 + 2];
      v.w = acc[i][jj * 4 + 3] + cb[tx * 4 + jj * 64 + 3];
      *(float4*)(dst + jj * 64) = v;
    }
  }
}

// ---------------- K2: double softmax_one window pooling ----------------
__global__ __launch_bounds__(256) void k_winpool(
    const float* __restrict__ x, float* __restrict__ imagew)
{
  __shared__ float Xs[64][132];     // half of channels at a time
  __shared__ float cor[64][65];
  __shared__ float wgt[64];
  const int bwin = blockIdx.x;
  const int tid = threadIdx.x;
  const int ty = tid >> 4, tx = tid & 15;
  const float* xw = x + (size_t)bwin * 16384;

  float acc[4][4];
#pragma unroll
  for (int i = 0; i < 4; ++i)
#pragma unroll
    for (int j = 0; j < 4; ++j) acc[i][j] = 0.f;

  for (int half = 0; half < 2; ++half) {
    {
      const int t = tid >> 2, c4 = tid & 3;
      const float* src = xw + t * 256 + half * 128;
#pragma unroll
      for (int i = 0; i < 8; ++i) {
        const int chunk = c4 + 4 * i;
        *(float4*)&Xs[t][chunk * 4] = *(const float4*)(src + chunk * 4);
      }
    }
    __syncthreads();
    for (int c = 0; c < 128; c += 4) {
      float4 av[4], bv[4];
#pragma unroll
      for (int i = 0; i < 4; ++i) av[i] = *(const float4*)&Xs[ty + 16 * i][c];
#pragma unroll
      for (int j = 0; j < 4; ++j) bv[j] = *(const float4*)&Xs[tx + 16 * j][c];
#pragma unroll
      for (int i = 0; i < 4; ++i)
#pragma unroll
        for (int j = 0; j < 4; ++j)
          acc[i][j] += av[i].x * bv[j].x + av[i].y * bv[j].y +
                       av[i].z * bv[j].z + av[i].w * bv[j].w;
    }
    __syncthreads();
  }
  const float sc = 0.0625f;   // DKV^-0.5
#pragma unroll
  for (int i = 0; i < 4; ++i)
#pragma unroll
    for (int j = 0; j < 4; ++j) cor[ty + 16 * i][tx + 16 * j] = acc[i][j] * sc;
  __syncthreads();
  // row softmax_one (over q), then normalized values stored back
  if (tid < 64) {
    const int p = tid;
    float m = -INFINITY;
    for (int qq = 0; qq < 64; ++qq) m = fmaxf(m, cor[p][qq]);
    float s = 0.f;
    for (int qq = 0; qq < 64; ++qq) { const float e = expf(cor[p][qq] - m); cor[p][qq] = e; s += e; }
    const float inv = 1.f / (1.f + s);
    for (int qq = 0; qq < 64; ++qq) cor[p][qq] *= inv;
  }
  __syncthreads();
  // column sums over p, then softmax_one over the 64 sums (wave 0)
  if (tid < 64) {
    const int qq = tid;
    float s = 0.f;
    for (int p = 0; p < 64; ++p) s += cor[p][qq];
    float m = s;
#pragma unroll
    for (int o = 1; o < 64; o <<= 1) m = fmaxf(m, __shfl_xor(m, o));
    const float e = expf(s - m);
    float tsum = e;
#pragma unroll
    for (int o = 1; o < 64; o <<= 1) tsum += __shfl_xor(tsum, o);
    wgt[qq] = e / (1.f + tsum);
  }
  __syncthreads();
  // imagew[c] = sum_q wgt[q] * x[q][c]  (x re-read from global, L2-hot)
  {
    const int c = tid;
    float a = 0.f;
    for (int qq = 0; qq < 64; ++qq) a += wgt[qq] * xw[qq * 256 + c];
    imagew[(size_t)bwin * 256 + c] = a;
  }
}

// ---------------- K3: row LayerNorm (rows of 256) ----------------
__global__ __launch_bounds__(256) void k_ln(
    const float* __restrict__ in, const float* __restrict__ g,
    const float* __restrict__ bb, float* __restrict__ out)
{
  const int row = blockIdx.x, tid = threadIdx.x;
  const float v = in[(size_t)row * 256 + tid];
  float s = v, s2 = v * v;
#pragma unroll
  for (int o = 1; o < 64; o <<= 1) { s += __shfl_xor(s, o); s2 += __shfl_xor(s2, o); }
  __shared__ float ps[4], ps2[4];
  if ((tid & 63) == 0) { ps[tid >> 6] = s; ps2[tid >> 6] = s2; }
  __syncthreads();
  const float S = ps[0] + ps[1] + ps[2] + ps[3];
  const float S2 = ps2[0] + ps2[1] + ps2[2] + ps2[3];
  const float mu = S * (1.f / 256.f);
  const float rs = rsqrtf(S2 * (1.f / 256.f) - mu * mu + 1e-5f);
  out[(size_t)row * 256 + tid] = (v - mu) * rs * g[tid] + bb[tid];
}

// ---------------- K4: generic tiled GEMM  C = act(A @ B^T * scale + bias) + res ----------------
template <bool BIAS, bool RELU, bool RES>
__global__ __launch_bounds__(256) void k_gemm(
    const float* __restrict__ A, const float* __restrict__ B,
    const float* __restrict__ bias, const float* __restrict__ res,
    float* __restrict__ C, int M, int N, int K, float scale,
    long aZ, long bZ, long cZ)
{
  A += (size_t)blockIdx.z * aZ;
  B += (size_t)blockIdx.z * bZ;
  C += (size_t)blockIdx.z * cZ;
  const float* R = RES ? res + (size_t)blockIdx.z * cZ : nullptr;
  __shared__ float As[32][65], Bs[32][65];   // k-major, odd stride: conflict-free scalar
  const int m0 = blockIdx.x * 64, n0 = blockIdx.y * 64;
  const int tid = threadIdx.x;
  const int ty = tid >> 4, tx = tid & 15;
  const int r = tid >> 3, gq = tid & 7;
  float acc[4][4];
#pragma unroll
  for (int i = 0; i < 4; ++i)
#pragma unroll
    for (int j = 0; j < 4; ++j) acc[i][j] = 0.f;

  for (int kc = 0; kc < K; kc += 32) {
#pragma unroll
    for (int hf = 0; hf < 2; ++hf) {
      const int row = r + hf * 32;
      const float4 va = *(const float4*)(A + (size_t)(m0 + row) * K + kc + gq * 4);
      As[gq * 4 + 0][row] = va.x; As[gq * 4 + 1][row] = va.y;
      As[gq * 4 + 2][row] = va.z; As[gq * 4 + 3][row] = va.w;
      const float4 vb = *(const float4*)(B + (size_t)(n0 + row) * K + kc + gq * 4);
      Bs[gq * 4 + 0][row] = vb.x; Bs[gq * 4 + 1][row] = vb.y;
      Bs[gq * 4 + 2][row] = vb.z; Bs[gq * 4 + 3][row] = vb.w;
    }
    __syncthreads();
#pragma unroll
    for (int kk = 0; kk < 32; ++kk) {
      float a[4], bb2[4];
#pragma unroll
      for (int i = 0; i < 4; ++i) a[i] = As[kk][ty + 16 * i];
#pragma unroll
      for (int j = 0; j < 4; ++j) bb2[j] = Bs[kk][tx + 16 * j];
#pragma unroll
      for (int i = 0; i < 4; ++i)
#pragma unroll
        for (int j = 0; j < 4; ++j) acc[i][j] += a[i] * bb2[j];
    }
    __syncthreads();
  }
#pragma unroll
  for (int i = 0; i < 4; ++i) {
    const int mi = m0 + ty + 16 * i;
#pragma unroll
    for (int j = 0; j < 4; ++j) {
      const int nj = n0 + tx + 16 * j;
      float v = acc[i][j] * scale;
      if (BIAS) v += bias[nj];
      if (RELU) v = fmaxf(v, 0.f);
      if (RES) v += R[(size_t)mi * N + nj];
      C[(size_t)mi * N + nj] = v;
    }
  }
}

// ---------------- K5: top-4 window routing (matches lax.top_k tie-break) ----------------
__global__ __launch_bounds__(256) void k_topk(
    const float* __restrict__ rattn, int* __restrict__ outi)
{
  const int pair = blockIdx.x * 4 + (threadIdx.x >> 6);   // (b*256+q)
  const int lane = threadIdx.x & 63;
  const float* rp = rattn + (size_t)pair * 256;
  float v[4];
#pragma unroll
  for (int i = 0; i < 4; ++i) v[i] = rp[i * 64 + lane];
  int selmask = 0;
  for (int rsel = 0; rsel < 4; ++rsel) {
    float bv = -INFINITY; int bi = 1 << 30;
#pragma unroll
    for (int i = 0; i < 4; ++i) {
      if (!(selmask & (1 << i))) {
        const float val = v[i]; const int idx = i * 64 + lane;
        if (val > bv || (val == bv && idx < bi)) { bv = val; bi = idx; }
      }
    }
#pragma unroll
    for (int o = 1; o < 64; o <<= 1) {
      const float ov = __shfl_xor(bv, o); const int oi = __shfl_xor(bi, o);
      if (ov > bv || (ov == bv && oi < bi)) { bv = ov; bi = oi; }
    }
    if (lane == 0) outi[pair * 4 + rsel] = bi;
    if (lane == (bi & 63)) selmask |= 1 << (bi >> 6);
  }
}

// ---------------- K6: fused gather + LN-folded attention per (b,q) ----------------
// dots = (Wk^T q)_h . kv ; pooled = sum attn*kv ; out = Wv . pooled. LN folded algebraically.
__global__ __launch_bounds__(256) void k_attn(
    const float* __restrict__ qp, const int* __restrict__ topidx,
    const float* __restrict__ x, const float* __restrict__ pos,
    const float* __restrict__ nkg, const float* __restrict__ nkb,
    const float* __restrict__ wk, const float* __restrict__ wvT,
    float* __restrict__ attnout)
{
  __shared__ float qrow[256];
  __shared__ float qWg[8][260];       // chunk-swizzled (see qwg offset)
  __shared__ float Raw[32][260];
  __shared__ float pooled[8][256];
  __shared__ float dts[8][32];
  __shared__ float muT[32], rsT[32];
  __shared__ float Gh[8], qWb[8], mh[8], lh[8], S1[8], scl[8];

  const int bq = blockIdx.x;
  const int b = bq >> 8;
  const int tid = threadIdx.x;

  qrow[tid] = qp[(size_t)bq * 256 + tid];
#pragma unroll
  for (int h = 0; h < 8; ++h) pooled[h][tid] = 0.f;
  if (tid < 8) { Gh[tid] = 0.f; qWb[tid] = 0.f; mh[tid] = -INFINITY; lh[tid] = 0.f; S1[tid] = 0.f; }
  __syncthreads();

  // per-head folded query: qWg[h][c] = (sum_j q[h*32+j] wk[h*32+j][c]) * DH^-0.5 * g[c]
  {
    const float qs = 0.17677669529663689f;  // 1/sqrt(32)
    const float gc = nkg[tid], bc = nkb[tid];
    const int ch = tid >> 2, lo = tid & 3;
    const int off = (((ch & 7) << 3) | (ch >> 3)) * 4 + lo;   // 3-3 bit-swap chunk swizzle
#pragma unroll
    for (int h = 0; h < 8; ++h) {
      float a = 0.f;
#pragma unroll
      for (int j = 0; j < 32; ++j)
        a += qrow[h * 32 + j] * wk[(size_t)(h * 32 + j) * 256 + tid];
      a *= qs;
      qWg[h][off] = a * gc;
      float v1 = a * gc, v2 = a * bc;
#pragma unroll
      for (int o = 1; o < 64; o <<= 1) { v1 += __shfl_xor(v1, o); v2 += __shfl_xor(v2, o); }
      if ((tid & 63) == 0) { atomicAdd(&Gh[h], v1); atomicAdd(&qWb[h], v2); }
    }
  }
  __syncthreads();

  for (int tile = 0; tile < 8; ++tile) {          // 4 windows x 2 half-tiles of 32 tokens
    const int w = tile >> 1, th = tile & 1;
    const int win = topidx[bq * 4 + w];
    // stage raw = x + pos, with per-token stats
    {
      const int tt = tid >> 3, c8 = tid & 7;
      const float* xs = x + ((size_t)(b * 256 + win) * 64 + th * 32 + tt) * 256;
      const float* ps = pos + (size_t)(w * 64 + th * 32 + tt) * 256;
      float s = 0.f, s2 = 0.f;
#pragma unroll
      for (int i = 0; i < 8; ++i) {
        const int ck = c8 + 8 * i;
        float4 v = *(const float4*)(xs + ck * 4);
        const float4 p4 = *(const float4*)(ps + ck * 4);
        v.x += p4.x; v.y += p4.y; v.z += p4.z; v.w += p4.w;
        *(float4*)&Raw[tt][ck * 4] = v;
        s += v.x + v.y + v.z + v.w;
        s2 += v.x * v.x + v.y * v.y + v.z * v.z + v.w * v.w;
      }
#pragma unroll
      for (int o = 1; o < 8; o <<= 1) { s += __shfl_xor(s, o); s2 += __shfl_xor(s2, o); }
      if (c8 == 0) {
        const float mu = s * (1.f / 256.f);
        muT[tt] = mu;
        rsT[tt] = rsqrtf(s2 * (1.f / 256.f) - mu * mu + 1e-5f);
      }
    }
    __syncthreads();
    // dots for 8 heads x 32 tokens; each thread = (token, c-slice of 32)
    {
      const int tt = tid >> 3, cq = tid & 7;
      float ds[8];
#pragma unroll
      for (int h = 0; h < 8; ++h) ds[h] = 0.f;
#pragma unroll
      for (int ch = 0; ch < 8; ++ch) {
        const float4 rv = *(const float4*)&Raw[tt][cq * 32 + ch * 4];
#pragma unroll
        for (int h = 0; h < 8; ++h) {
          const float4 qv = *(const float4*)&qWg[h][32 * ch + 4 * cq];
          ds[h] += rv.x * qv.x + rv.y * qv.y + rv.z * qv.z + rv.w * qv.w;
        }
      }
#pragma unroll
      for (int o = 1; o < 8; o <<= 1)
#pragma unroll
        for (int h = 0; h < 8; ++h) ds[h] += __shfl_xor(ds[h], o);
      if (cq == 0) {
        const float rs = rsT[tt], mu = muT[tt];
#pragma unroll
        for (int h = 0; h < 8; ++h)
          dts[h][tt] = rs * ds[h] - rs * mu * Gh[h] + qWb[h];
      }
    }
    __syncthreads();
    // online softmax update per head
    {
      const int h = tid >> 5, tt = tid & 31;
      const float d = dts[h][tt];
      float tm = d;
#pragma unroll
      for (int o = 1; o < 32; o <<= 1) tm = fmaxf(tm, __shfl_xor(tm, o));
      const float mold = mh[h];
      const float mnew = fmaxf(mold, tm);
      const float e = expf(d - mnew);
      const float wE = e * rsT[tt];
      dts[h][tt] = wE;                 // weight for pooled accumulation
      float s1 = e, s2 = wE * muT[tt];
#pragma unroll
      for (int o = 1; o < 32; o <<= 1) { s1 += __shfl_xor(s1, o); s2 += __shfl_xor(s2, o); }
      if (tt == 0) {
        const float f = expf(mold - mnew);
        lh[h] = lh[h] * f + s1;
        S1[h] = S1[h] * f + s2;
        mh[h] = mnew;
        scl[h] = f;
      }
    }
    __syncthreads();
    // pooled[h][c] = pooled*f + sum_t wE[t]*raw[t][c]
    {
      const int h = tid >> 5, cg = tid & 31;
      const float f = scl[h];
#pragma unroll
      for (int rep = 0; rep < 2; ++rep) {
        const int c = cg * 4 + rep * 128;
        float4 p = *(const float4*)&pooled[h][c];
        p.x *= f; p.y *= f; p.z *= f; p.w *= f;
#pragma unroll 8
        for (int t2 = 0; t2 < 32; ++t2) {
          const float wE = dts[h][t2];
          const float4 rv = *(const float4*)&Raw[t2][c];
          p.x += wE * rv.x; p.y += wE * rv.y; p.z += wE * rv.z; p.w += wE * rv.w;
        }
        *(float4*)&pooled[h][c] = p;
      }
    }
    __syncthreads();
  }
  // finalize: pf = g*(praw - S1)/l + b  (softmax sums to 1)
  {
    const int h = tid >> 5, cg = tid & 31;
    const float linv = 1.f / lh[h];
    const float s1v = S1[h];
#pragma unroll
    for (int rep = 0; rep < 8; ++rep) {
      const int c = cg + rep * 32;
      pooled[h][c] = nkg[c] * (pooled[h][c] - s1v) * linv + nkb[c];
    }
  }
  __syncthreads();
  // attnout[j] = sum_c pf[h(j)][c] * wv[j][c]   (wvT is wv transposed)
  {
    const int j = tid, h = j >> 5;
    float a = 0.f;
    for (int c = 0; c < 256; ++c)
      a += pooled[h][c] * wvT[(size_t)c * 256 + j];
    attnout[(size_t)bq * 256 + j] = a;
  }
}

// ---------------- K7: 256x256 transpose (wv -> wvT) ----------------
__global__ void k_transpose256(const float* __restrict__ in, float* __restrict__ out)
{
  __shared__ float tile[32][33];
  const int bx = blockIdx.x * 32, by = blockIdx.y * 32;
  const int tx = threadIdx.x, ty = threadIdx.y;
#pragma unroll
  for (int i = 0; i < 32; i += 8)
    tile[ty + i][tx] = in[(size_t)(by + ty + i) * 256 + bx + tx];
  __syncthreads();
#pragma unroll
  for (int i = 0; i < 32; i += 8)
    out[(size_t)(bx + ty + i) * 256 + by + tx] = tile[tx][ty + i];
}

// ---------------- launch ----------------
extern "C" void kernel_launch(void* const* d_in, const int* in_sizes, int n_in,
                              void* d_out, int out_size, void* d_ws, size_t ws_size,
                              hipStream_t stream)
{
  const float* query   = (const float*)d_in[0];
  const float* image   = (const float*)d_in[1];
  const float* conv_w  = (const float*)d_in[2];
  const float* conv_b  = (const float*)d_in[3];
  const float* pos     = (const float*)d_in[4];
  const float* normq_g = (const float*)d_in[5];
  const float* normq_b = (const float*)d_in[6];
  const float* normkv_g= (const float*)d_in[7];
  const float* normkv_b= (const float*)d_in[8];
  const float* wq      = (const float*)d_in[9];
  const float* wk      = (const float*)d_in[10];
  const float* wv      = (const float*)d_in[11];
  const float* w_rec   = (const float*)d_in[12];
  const float* mlp_g   = (const float*)d_in[13];
  const float* mlp_b   = (const float*)d_in[14];
  const float* mlp_w1  = (const float*)d_in[15];
  const float* mlp_b1  = (const float*)d_in[16];
  const float* mlp_w2  = (const float*)d_in[17];
  const float* mlp_b2  = (const float*)d_in[18];
  float* out = (float*)d_out;

  float* ws = (float*)d_ws;
  float* x      = ws;                    // 16,777,216 f
  float* imagew = x + 16777216;          // 262,144 f
  float* qln    = imagew + 262144;
  float* qproj  = qln + 262144;
  float* rattn  = qproj + 262144;
  float* attno  = rattn + 262144;
  float* outmid = attno + 262144;
  float* mlpln  = outmid + 262144;
  float* h1     = mlpln + 262144;
  float* wvT    = h1 + 262144;           // 65,536 f
  int*   topidx = (int*)(wvT + 65536);   // 4,096 i32

  // 1) conv patchify -> x (windowed layout)
  k_conv<<<512, 256, 0, stream>>>(image, conv_w, conv_b, x);
  // prep: transpose wv for coalesced epilogue reads
  k_transpose256<<<dim3(8, 8), dim3(32, 8), 0, stream>>>(wv, wvT);
  // 2) window pooling -> imagew
  k_winpool<<<1024, 256, 0, stream>>>(x, imagew);
  // 3) q = LN(query) @ wq^T
  k_ln<<<1024, 256, 0, stream>>>(query, normq_g, normq_b, qln);
  k_gemm<false, false, false><<<dim3(16, 4, 1), 256, 0, stream>>>(
      qln, wq, nullptr, nullptr, qproj, 1024, 256, 256, 1.f, 0, 0, 0);
  // routing scores + top-4
  k_gemm<false, false, false><<<dim3(4, 4, 4), 256, 0, stream>>>(
      qproj, imagew, nullptr, nullptr, rattn, 256, 256, 256, 0.0625f,
      65536, 65536, 65536);
  k_topk<<<256, 256, 0, stream>>>(rattn, topidx);
  // 4+5) fused gather + LN + attention (K/V projections folded)
  k_attn<<<1024, 256, 0, stream>>>(qproj, topidx, x, pos, normkv_g, normkv_b,
                                   wk, wvT, attno);
  // out = attno @ w_rec^T + query
  k_gemm<false, false, true><<<dim3(16, 4, 1), 256, 0, stream>>>(
      attno, w_rec, nullptr, query, outmid, 1024, 256, 256, 1.f, 0, 0, 0);
  // 6) residual MLP
  k_ln<<<1024, 256, 0, stream>>>(outmid, mlp_g, mlp_b, mlpln);
  k_gemm<true, true, false><<<dim3(16, 4, 1), 256, 0, stream>>>(
      mlpln, mlp_w1, mlp_b1, nullptr, h1, 1024, 256, 256, 1.f, 0, 0, 0);
  k_gemm<true, false, true><<<dim3(16, 4, 1), 256, 0, stream>>>(
      h1, mlp_w2, mlp_b2, outmid, out, 1024, 256, 256, 1.f, 0, 0, 0);
}

// Round 2
// 741.846 us; speedup vs baseline: 1.3890x; 1.3890x over previous
//
#include <hip/hip_runtime.h>
#include <math.h>

// Problem constants
// B=4, NQ=256, DQ=256, DKV=256, H_IMG=W_IMG=256, HEADS=8, DH=32,
// TOPW=4, WS=8, FACTOR=2, INNER=256, DOUT=256
// conv out spatial: 128x128 -> M=N=16 windows of 64 dilated tokens.
// x layout: [bwin(1024)][t(64)][c(256)], bwin = b*256 + m*16 + n, t = h*8+w,
// pixel (y,x) = (h*16+m, w*16+n).

typedef __bf16 bf16x8_t __attribute__((ext_vector_type(8)));
typedef float f32x4 __attribute__((ext_vector_type(4)));
typedef unsigned short ushortx8 __attribute__((ext_vector_type(8)));
typedef unsigned short ushortx4 __attribute__((ext_vector_type(4)));

__device__ __forceinline__ unsigned short f2bf(float f) {
  unsigned int u = __float_as_uint(f);
  unsigned int r = (u + 0x7FFFu + ((u >> 16) & 1u)) >> 16;   // RNE
  return (unsigned short)r;
}
__device__ __forceinline__ float bf2f(unsigned short h) {
  return __uint_as_float(((unsigned int)h) << 16);
}

#define MFMA16(a, b, c) \
  __builtin_amdgcn_mfma_f32_16x16x32_bf16( \
      __builtin_bit_cast(bf16x8_t, (a)), __builtin_bit_cast(bf16x8_t, (b)), (c), 0, 0, 0)

// ---------------- K0: pre-split conv weights to bf16 hi/lo ----------------
__global__ __launch_bounds__(256) void k_prepw(
    const float* __restrict__ cw, unsigned short* __restrict__ cwh,
    unsigned short* __restrict__ cwl)
{
  const int o = blockIdx.x;
  const int k4 = threadIdx.x * 4;
  const float4 w = *(const float4*)(cw + (size_t)o * 1024 + k4);
  float f[4] = {w.x, w.y, w.z, w.w};
  ushortx4 h, l;
#pragma unroll
  for (int i = 0; i < 4; ++i) {
    h[i] = f2bf(f[i]);
    l[i] = f2bf(f[i] - bf2f(h[i]));
  }
  *(ushortx4*)(cwh + (size_t)o * 1024 + k4) = h;
  *(ushortx4*)(cwl + (size_t)o * 1024 + k4) = l;
}

// ---------------- K1: conv patchify as split-bf16 MFMA implicit GEMM ----------------
// GEMM: M=65536 spatial (block: 128 x-positions at fixed (b,y)), N=256 (block: 128),
// K=1024 (cin*ky*kx), BK=32. a = a_hi + a_lo; acc += ah*bh + al*bh + ah*bl.
__global__ __launch_bounds__(512, 4) void k_conv(
    const float* __restrict__ img, const unsigned short* __restrict__ cwh,
    const unsigned short* __restrict__ cwl, const float* __restrict__ cb,
    float* __restrict__ x)
{
  __shared__ unsigned short Ah[128 * 40];   // [m][k] stride 40 bf16 (80 B)
  __shared__ unsigned short Al[128 * 40];
  __shared__ unsigned short Bh[128 * 40];   // [n][k]
  __shared__ unsigned short Bl[128 * 40];

  const int tid = threadIdx.x;
  const int blk = blockIdx.x;          // 1024 = 512 (b,y) rows x 2 n-halves
  const int nh = blk & 1, by = blk >> 1;
  const int b = by >> 7, y = by & 127;
  const int n0 = nh * 128;

  // wave decomposition: 8 waves = 2 (M) x 4 (N); wave tile 64x32 = 4x2 frags
  const int lane = tid & 63, wid = tid >> 6;
  const int wr = wid >> 2, wc = wid & 3;
  const int lr = lane & 15, lk = lane >> 4;

  // A staging map: thread -> (x pos, ci-pair)
  const int ax = tid & 127, aq = tid >> 7;       // aq in 0..3 -> ci0 = aq*2
  const float* abase = img + (size_t)b * 16777216 + (size_t)(2 * y) * 256 + 2 * ax;
  // B staging map: thread -> (o, k-quarter)
  const int bo = tid >> 2, bkq = tid & 3;

  f32x4 acc[4][2];
#pragma unroll
  for (int i = 0; i < 4; ++i)
#pragma unroll
    for (int j = 0; j < 2; ++j) acc[i][j] = (f32x4){0.f, 0.f, 0.f, 0.f};

  for (int kc = 0; kc < 32; ++kc) {
    __syncthreads();
    // ---- stage A: 8 floats/thread -> hi/lo bf16, k = ci*4 + ky*2 + kx ----
    {
      float f[8];
#pragma unroll
      for (int cc = 0; cc < 2; ++cc) {
        const int cin = kc * 8 + aq * 2 + cc;
        const float* p = abase + (size_t)cin * 65536;
        const float2 v0 = *(const float2*)p;          // ky=0
        const float2 v1 = *(const float2*)(p + 256);  // ky=1
        f[cc * 4 + 0] = v0.x; f[cc * 4 + 1] = v0.y;
        f[cc * 4 + 2] = v1.x; f[cc * 4 + 3] = v1.y;
      }
      ushortx8 h, l;
#pragma unroll
      for (int i = 0; i < 8; ++i) {
        h[i] = f2bf(f[i]);
        l[i] = f2bf(f[i] - bf2f(h[i]));
      }
      *(ushortx8*)&Ah[ax * 40 + aq * 8] = h;
      *(ushortx8*)&Al[ax * 40 + aq * 8] = l;
    }
    // ---- stage B: prepacked hi/lo, 16B copies ----
    {
      const size_t goff = (size_t)(n0 + bo) * 1024 + kc * 32 + bkq * 8;
      *(ushortx8*)&Bh[bo * 40 + bkq * 8] = *(const ushortx8*)(cwh + goff);
      *(ushortx8*)&Bl[bo * 40 + bkq * 8] = *(const ushortx8*)(cwl + goff);
    }
    __syncthreads();
    // ---- fragments + 3-term split MFMA ----
    ushortx8 bh2[2], bl2[2];
#pragma unroll
    for (int ni = 0; ni < 2; ++ni) {
      const int col = wc * 32 + ni * 16 + lr;
      bh2[ni] = *(ushortx8*)&Bh[col * 40 + lk * 8];
      bl2[ni] = *(ushortx8*)&Bl[col * 40 + lk * 8];
    }
#pragma unroll
    for (int mi = 0; mi < 4; ++mi) {
      const int row = wr * 64 + mi * 16 + lr;
      const ushortx8 ah = *(ushortx8*)&Ah[row * 40 + lk * 8];
      const ushortx8 al = *(ushortx8*)&Al[row * 40 + lk * 8];
#pragma unroll
      for (int ni = 0; ni < 2; ++ni) {
        acc[mi][ni] = MFMA16(ah, bh2[ni], acc[mi][ni]);
        acc[mi][ni] = MFMA16(al, bh2[ni], acc[mi][ni]);
        acc[mi][ni] = MFMA16(ah, bl2[ni], acc[mi][ni]);
      }
    }
  }
  // ---- epilogue: + bias, scatter into dilated-window layout ----
  const int hh = y >> 4, mm = y & 15;
#pragma unroll
  for (int mi = 0; mi < 4; ++mi) {
    const int pbase = wr * 64 + mi * 16 + lk * 4;
#pragma unroll
    for (int ni = 0; ni < 2; ++ni) {
      const int c = n0 + wc * 32 + ni * 16 + lr;
      const float cbv = cb[c];
#pragma unroll
      for (int r = 0; r < 4; ++r) {
        const int p = pbase + r;
        const int w = p >> 4, n = p & 15;
        const int bwin = b * 256 + mm * 16 + n;
        const int t = hh * 8 + w;
        x[(size_t)(bwin * 64 + t) * 256 + c] = acc[mi][ni][r] + cbv;
      }
    }
  }
}

// ---------------- K2: double softmax_one window pooling ----------------
__global__ __launch_bounds__(256) void k_winpool(
    const float* __restrict__ x, float* __restrict__ imagew)
{
  __shared__ float Xs[64][132];     // half of channels at a time
  __shared__ float cor[64][65];
  __shared__ float wgt[64];
  const int bwin = blockIdx.x;
  const int tid = threadIdx.x;
  const int ty = tid >> 4, tx = tid & 15;
  const float* xw = x + (size_t)bwin * 16384;

  float acc[4][4];
#pragma unroll
  for (int i = 0; i < 4; ++i)
#pragma unroll
    for (int j = 0; j < 4; ++j) acc[i][j] = 0.f;

  for (int half = 0; half < 2; ++half) {
    {
      const int t = tid >> 2, c4 = tid & 3;
      const float* src = xw + t * 256 + half * 128;
#pragma unroll
      for (int i = 0; i < 8; ++i) {
        const int chunk = c4 + 4 * i;
        *(float4*)&Xs[t][chunk * 4] = *(const float4*)(src + chunk * 4);
      }
    }
    __syncthreads();
    for (int c = 0; c < 128; c += 4) {
      float4 av[4], bv[4];
#pragma unroll
      for (int i = 0; i < 4; ++i) av[i] = *(const float4*)&Xs[ty + 16 * i][c];
#pragma unroll
      for (int j = 0; j < 4; ++j) bv[j] = *(const float4*)&Xs[tx + 16 * j][c];
#pragma unroll
      for (int i = 0; i < 4; ++i)
#pragma unroll
        for (int j = 0; j < 4; ++j)
          acc[i][j] += av[i].x * bv[j].x + av[i].y * bv[j].y +
                       av[i].z * bv[j].z + av[i].w * bv[j].w;
    }
    __syncthreads();
  }
  const float sc = 0.0625f;   // DKV^-0.5
#pragma unroll
  for (int i = 0; i < 4; ++i)
#pragma unroll
    for (int j = 0; j < 4; ++j) cor[ty + 16 * i][tx + 16 * j] = acc[i][j] * sc;
  __syncthreads();
  // row softmax_one (over q), then normalized values stored back
  if (tid < 64) {
    const int p = tid;
    float m = -INFINITY;
    for (int qq = 0; qq < 64; ++qq) m = fmaxf(m, cor[p][qq]);
    float s = 0.f;
    for (int qq = 0; qq < 64; ++qq) { const float e = expf(cor[p][qq] - m); cor[p][qq] = e; s += e; }
    const float inv = 1.f / (1.f + s);
    for (int qq = 0; qq < 64; ++qq) cor[p][qq] *= inv;
  }
  __syncthreads();
  // column sums over p, then softmax_one over the 64 sums (wave 0)
  if (tid < 64) {
    const int qq = tid;
    float s = 0.f;
    for (int p = 0; p < 64; ++p) s += cor[p][qq];
    float m = s;
#pragma unroll
    for (int o = 1; o < 64; o <<= 1) m = fmaxf(m, __shfl_xor(m, o));
    const float e = expf(s - m);
    float tsum = e;
#pragma unroll
    for (int o = 1; o < 64; o <<= 1) tsum += __shfl_xor(tsum, o);
    wgt[qq] = e / (1.f + tsum);
  }
  __syncthreads();
  // imagew[c] = sum_q wgt[q] * x[q][c]  (x re-read from global, L2-hot)
  {
    const int c = tid;
    float a = 0.f;
    for (int qq = 0; qq < 64; ++qq) a += wgt[qq] * xw[qq * 256 + c];
    imagew[(size_t)bwin * 256 + c] = a;
  }
}

// ---------------- K3: row LayerNorm (rows of 256) ----------------
__global__ __launch_bounds__(256) void k_ln(
    const float* __restrict__ in, const float* __restrict__ g,
    const float* __restrict__ bb, float* __restrict__ out)
{
  const int row = blockIdx.x, tid = threadIdx.x;
  const float v = in[(size_t)row * 256 + tid];
  float s = v, s2 = v * v;
#pragma unroll
  for (int o = 1; o < 64; o <<= 1) { s += __shfl_xor(s, o); s2 += __shfl_xor(s2, o); }
  __shared__ float ps[4], ps2[4];
  if ((tid & 63) == 0) { ps[tid >> 6] = s; ps2[tid >> 6] = s2; }
  __syncthreads();
  const float S = ps[0] + ps[1] + ps[2] + ps[3];
  const float S2 = ps2[0] + ps2[1] + ps2[2] + ps2[3];
  const float mu = S * (1.f / 256.f);
  const float rs = rsqrtf(S2 * (1.f / 256.f) - mu * mu + 1e-5f);
  out[(size_t)row * 256 + tid] = (v - mu) * rs * g[tid] + bb[tid];
}

// ---------------- K4: generic tiled GEMM  C = act(A @ B^T * scale + bias) + res ----------------
template <bool BIAS, bool RELU, bool RES>
__global__ __launch_bounds__(256) void k_gemm(
    const float* __restrict__ A, const float* __restrict__ B,
    const float* __restrict__ bias, const float* __restrict__ res,
    float* __restrict__ C, int M, int N, int K, float scale,
    long aZ, long bZ, long cZ)
{
  A += (size_t)blockIdx.z * aZ;
  B += (size_t)blockIdx.z * bZ;
  C += (size_t)blockIdx.z * cZ;
  const float* R = RES ? res + (size_t)blockIdx.z * cZ : nullptr;
  __shared__ float As[32][65], Bs[32][65];   // k-major, odd stride: conflict-free scalar
  const int m0 = blockIdx.x * 64, n0 = blockIdx.y * 64;
  const int tid = threadIdx.x;
  const int ty = tid >> 4, tx = tid & 15;
  const int r = tid >> 3, gq = tid & 7;
  float acc[4][4];
#pragma unroll
  for (int i = 0; i < 4; ++i)
#pragma unroll
    for (int j = 0; j < 4; ++j) acc[i][j] = 0.f;

  for (int kc = 0; kc < K; kc += 32) {
#pragma unroll
    for (int hf = 0; hf < 2; ++hf) {
      const int row = r + hf * 32;
      const float4 va = *(const float4*)(A + (size_t)(m0 + row) * K + kc + gq * 4);
      As[gq * 4 + 0][row] = va.x; As[gq * 4 + 1][row] = va.y;
      As[gq * 4 + 2][row] = va.z; As[gq * 4 + 3][row] = va.w;
      const float4 vb = *(const float4*)(B + (size_t)(n0 + row) * K + kc + gq * 4);
      Bs[gq * 4 + 0][row] = vb.x; Bs[gq * 4 + 1][row] = vb.y;
      Bs[gq * 4 + 2][row] = vb.z; Bs[gq * 4 + 3][row] = vb.w;
    }
    __syncthreads();
#pragma unroll
    for (int kk = 0; kk < 32; ++kk) {
      float a[4], bb2[4];
#pragma unroll
      for (int i = 0; i < 4; ++i) a[i] = As[kk][ty + 16 * i];
#pragma unroll
      for (int j = 0; j < 4; ++j) bb2[j] = Bs[kk][tx + 16 * j];
#pragma unroll
      for (int i = 0; i < 4; ++i)
#pragma unroll
        for (int j = 0; j < 4; ++j) acc[i][j] += a[i] * bb2[j];
    }
    __syncthreads();
  }
#pragma unroll
  for (int i = 0; i < 4; ++i) {
    const int mi = m0 + ty + 16 * i;
#pragma unroll
    for (int j = 0; j < 4; ++j) {
      const int nj = n0 + tx + 16 * j;
      float v = acc[i][j] * scale;
      if (BIAS) v += bias[nj];
      if (RELU) v = fmaxf(v, 0.f);
      if (RES) v += R[(size_t)mi * N + nj];
      C[(size_t)mi * N + nj] = v;
    }
  }
}

// ---------------- K5: top-4 window routing (matches lax.top_k tie-break) ----------------
__global__ __launch_bounds__(256) void k_topk(
    const float* __restrict__ rattn, int* __restrict__ outi)
{
  const int pair = blockIdx.x * 4 + (threadIdx.x >> 6);   // (b*256+q)
  const int lane = threadIdx.x & 63;
  const float* rp = rattn + (size_t)pair * 256;
  float v[4];
#pragma unroll
  for (int i = 0; i < 4; ++i) v[i] = rp[i * 64 + lane];
  int selmask = 0;
  for (int rsel = 0; rsel < 4; ++rsel) {
    float bv = -INFINITY; int bi = 1 << 30;
#pragma unroll
    for (int i = 0; i < 4; ++i) {
      if (!(selmask & (1 << i))) {
        const float val = v[i]; const int idx = i * 64 + lane;
        if (val > bv || (val == bv && idx < bi)) { bv = val; bi = idx; }
      }
    }
#pragma unroll
    for (int o = 1; o < 64; o <<= 1) {
      const float ov = __shfl_xor(bv, o); const int oi = __shfl_xor(bi, o);
      if (ov > bv || (ov == bv && oi < bi)) { bv = ov; bi = oi; }
    }
    if (lane == 0) outi[pair * 4 + rsel] = bi;
    if (lane == (bi & 63)) selmask |= 1 << (bi >> 6);
  }
}

// ---------------- K6: fused gather + LN-folded attention per (b,q) ----------------
__global__ __launch_bounds__(256) void k_attn(
    const float* __restrict__ qp, const int* __restrict__ topidx,
    const float* __restrict__ x, const float* __restrict__ pos,
    const float* __restrict__ nkg, const float* __restrict__ nkb,
    const float* __restrict__ wk, const float* __restrict__ wvT,
    float* __restrict__ attnout)
{
  __shared__ float qrow[256];
  __shared__ float qWg[8][260];       // chunk-swizzled (see qwg offset)
  __shared__ float Raw[32][260];
  __shared__ float pooled[8][256];
  __shared__ float dts[8][32];
  __shared__ float muT[32], rsT[32];
  __shared__ float Gh[8], qWb[8], mh[8], lh[8], S1[8], scl[8];

  const int bq = blockIdx.x;
  const int b = bq >> 8;
  const int tid = threadIdx.x;

  qrow[tid] = qp[(size_t)bq * 256 + tid];
#pragma unroll
  for (int h = 0; h < 8; ++h) pooled[h][tid] = 0.f;
  if (tid < 8) { Gh[tid] = 0.f; qWb[tid] = 0.f; mh[tid] = -INFINITY; lh[tid] = 0.f; S1[tid] = 0.f; }
  __syncthreads();

  // per-head folded query: qWg[h][c] = (sum_j q[h*32+j] wk[h*32+j][c]) * DH^-0.5 * g[c]
  {
    const float qs = 0.17677669529663689f;  // 1/sqrt(32)
    const float gc = nkg[tid], bc = nkb[tid];
    const int ch = tid >> 2, lo = tid & 3;
    const int off = (((ch & 7) << 3) | (ch >> 3)) * 4 + lo;   // 3-3 bit-swap chunk swizzle
#pragma unroll
    for (int h = 0; h < 8; ++h) {
      float a = 0.f;
#pragma unroll
      for (int j = 0; j < 32; ++j)
        a += qrow[h * 32 + j] * wk[(size_t)(h * 32 + j) * 256 + tid];
      a *= qs;
      qWg[h][off] = a * gc;
      float v1 = a * gc, v2 = a * bc;
#pragma unroll
      for (int o = 1; o < 64; o <<= 1) { v1 += __shfl_xor(v1, o); v2 += __shfl_xor(v2, o); }
      if ((tid & 63) == 0) { atomicAdd(&Gh[h], v1); atomicAdd(&qWb[h], v2); }
    }
  }
  __syncthreads();

  for (int tile = 0; tile < 8; ++tile) {          // 4 windows x 2 half-tiles of 32 tokens
    const int w = tile >> 1, th = tile & 1;
    const int win = topidx[bq * 4 + w];
    // stage raw = x + pos, with per-token stats
    {
      const int tt = tid >> 3, c8 = tid & 7;
      const float* xs = x + ((size_t)(b * 256 + win) * 64 + th * 32 + tt) * 256;
      const float* ps = pos + (size_t)(w * 64 + th * 32 + tt) * 256;
      float s = 0.f, s2 = 0.f;
#pragma unroll
      for (int i = 0; i < 8; ++i) {
        const int ck = c8 + 8 * i;
        float4 v = *(const float4*)(xs + ck * 4);
        const float4 p4 = *(const float4*)(ps + ck * 4);
        v.x += p4.x; v.y += p4.y; v.z += p4.z; v.w += p4.w;
        *(float4*)&Raw[tt][ck * 4] = v;
        s += v.x + v.y + v.z + v.w;
        s2 += v.x * v.x + v.y * v.y + v.z * v.z + v.w * v.w;
      }
#pragma unroll
      for (int o = 1; o < 8; o <<= 1) { s += __shfl_xor(s, o); s2 += __shfl_xor(s2, o); }
      if (c8 == 0) {
        const float mu = s * (1.f / 256.f);
        muT[tt] = mu;
        rsT[tt] = rsqrtf(s2 * (1.f / 256.f) - mu * mu + 1e-5f);
      }
    }
    __syncthreads();
    // dots for 8 heads x 32 tokens; each thread = (token, c-slice of 32)
    {
      const int tt = tid >> 3, cq = tid & 7;
      float ds[8];
#pragma unroll
      for (int h = 0; h < 8; ++h) ds[h] = 0.f;
#pragma unroll
      for (int ch = 0; ch < 8; ++ch) {
        const float4 rv = *(const float4*)&Raw[tt][cq * 32 + ch * 4];
#pragma unroll
        for (int h = 0; h < 8; ++h) {
          const float4 qv = *(const float4*)&qWg[h][32 * ch + 4 * cq];
          ds[h] += rv.x * qv.x + rv.y * qv.y + rv.z * qv.z + rv.w * qv.w;
        }
      }
#pragma unroll
      for (int o = 1; o < 8; o <<= 1)
#pragma unroll
        for (int h = 0; h < 8; ++h) ds[h] += __shfl_xor(ds[h], o);
      if (cq == 0) {
        const float rs = rsT[tt], mu = muT[tt];
#pragma unroll
        for (int h = 0; h < 8; ++h)
          dts[h][tt] = rs * ds[h] - rs * mu * Gh[h] + qWb[h];
      }
    }
    __syncthreads();
    // online softmax update per head
    {
      const int h = tid >> 5, tt = tid & 31;
      const float d = dts[h][tt];
      float tm = d;
#pragma unroll
      for (int o = 1; o < 32; o <<= 1) tm = fmaxf(tm, __shfl_xor(tm, o));
      const float mold = mh[h];
      const float mnew = fmaxf(mold, tm);
      const float e = expf(d - mnew);
      const float wE = e * rsT[tt];
      dts[h][tt] = wE;                 // weight for pooled accumulation
      float s1 = e, s2 = wE * muT[tt];
#pragma unroll
      for (int o = 1; o < 32; o <<= 1) { s1 += __shfl_xor(s1, o); s2 += __shfl_xor(s2, o); }
      if (tt == 0) {
        const float f = expf(mold - mnew);
        lh[h] = lh[h] * f + s1;
        S1[h] = S1[h] * f + s2;
        mh[h] = mnew;
        scl[h] = f;
      }
    }
    __syncthreads();
    // pooled[h][c] = pooled*f + sum_t wE[t]*raw[t][c]
    {
      const int h = tid >> 5, cg = tid & 31;
      const float f = scl[h];
#pragma unroll
      for (int rep = 0; rep < 2; ++rep) {
        const int c = cg * 4 + rep * 128;
        float4 p = *(const float4*)&pooled[h][c];
        p.x *= f; p.y *= f; p.z *= f; p.w *= f;
#pragma unroll 8
        for (int t2 = 0; t2 < 32; ++t2) {
          const float wE = dts[h][t2];
          const float4 rv = *(const float4*)&Raw[t2][c];
          p.x += wE * rv.x; p.y += wE * rv.y; p.z += wE * rv.z; p.w += wE * rv.w;
        }
        *(float4*)&pooled[h][c] = p;
      }
    }
    __syncthreads();
  }
  // finalize: pf = g*(praw - S1)/l + b  (softmax sums to 1)
  {
    const int h = tid >> 5, cg = tid & 31;
    const float linv = 1.f / lh[h];
    const float s1v = S1[h];
#pragma unroll
    for (int rep = 0; rep < 8; ++rep) {
      const int c = cg + rep * 32;
      pooled[h][c] = nkg[c] * (pooled[h][c] - s1v) * linv + nkb[c];
    }
  }
  __syncthreads();
  // attnout[j] = sum_c pf[h(j)][c] * wv[j][c]   (wvT is wv transposed)
  {
    const int j = tid, h = j >> 5;
    float a = 0.f;
    for (int c = 0; c < 256; ++c)
      a += pooled[h][c] * wvT[(size_t)c * 256 + j];
    attnout[(size_t)bq * 256 + j] = a;
  }
}

// ---------------- K7: 256x256 transpose (wv -> wvT) ----------------
__global__ void k_transpose256(const float* __restrict__ in, float* __restrict__ out)
{
  __shared__ float tile[32][33];
  const int bx = blockIdx.x * 32, by = blockIdx.y * 32;
  const int tx = threadIdx.x, ty = threadIdx.y;
#pragma unroll
  for (int i = 0; i < 32; i += 8)
    tile[ty + i][tx] = in[(size_t)(by + ty + i) * 256 + bx + tx];
  __syncthreads();
#pragma unroll
  for (int i = 0; i < 32; i += 8)
    out[(size_t)(bx + ty + i) * 256 + by + tx] = tile[tx][ty + i];
}

// ---------------- launch ----------------
extern "C" void kernel_launch(void* const* d_in, const int* in_sizes, int n_in,
                              void* d_out, int out_size, void* d_ws, size_t ws_size,
                              hipStream_t stream)
{
  const float* query   = (const float*)d_in[0];
  const float* image   = (const float*)d_in[1];
  const float* conv_w  = (const float*)d_in[2];
  const float* conv_b  = (const float*)d_in[3];
  const float* pos     = (const float*)d_in[4];
  const float* normq_g = (const float*)d_in[5];
  const float* normq_b = (const float*)d_in[6];
  const float* normkv_g= (const float*)d_in[7];
  const float* normkv_b= (const float*)d_in[8];
  const float* wq      = (const float*)d_in[9];
  const float* wk      = (const float*)d_in[10];
  const float* wv      = (const float*)d_in[11];
  const float* w_rec   = (const float*)d_in[12];
  const float* mlp_g   = (const float*)d_in[13];
  const float* mlp_b   = (const float*)d_in[14];
  const float* mlp_w1  = (const float*)d_in[15];
  const float* mlp_b1  = (const float*)d_in[16];
  const float* mlp_w2  = (const float*)d_in[17];
  const float* mlp_b2  = (const float*)d_in[18];
  float* out = (float*)d_out;

  float* ws = (float*)d_ws;
  float* x      = ws;                    // 16,777,216 f
  float* imagew = x + 16777216;          // 262,144 f
  float* qln    = imagew + 262144;
  float* qproj  = qln + 262144;
  float* rattn  = qproj + 262144;
  float* attno  = rattn + 262144;
  float* outmid = attno + 262144;
  float* mlpln  = outmid + 262144;
  float* h1     = mlpln + 262144;
  float* wvT    = h1 + 262144;           // 65,536 f
  int*   topidx = (int*)(wvT + 65536);   // 4,096 i32
  // conv weight hi/lo aliased onto rattn (1 MB): consumed by k_conv before
  // rattn is written by the routing GEMM (stream-ordered, no overlap in time)
  unsigned short* cwh = (unsigned short*)rattn;   // 262,144 bf16 (512 KB)
  unsigned short* cwl = cwh + 262144;             // 262,144 bf16 (512 KB)

  // 0) split conv weights to bf16 hi/lo
  k_prepw<<<256, 256, 0, stream>>>(conv_w, cwh, cwl);
  // 1) conv patchify -> x (windowed layout), split-bf16 MFMA
  k_conv<<<1024, 512, 0, stream>>>(image, cwh, cwl, conv_b, x);
  // prep: transpose wv for coalesced epilogue reads
  k_transpose256<<<dim3(8, 8), dim3(32, 8), 0, stream>>>(wv, wvT);
  // 2) window pooling -> imagew
  k_winpool<<<1024, 256, 0, stream>>>(x, imagew);
  // 3) q = LN(query) @ wq^T
  k_ln<<<1024, 256, 0, stream>>>(query, normq_g, normq_b, qln);
  k_gemm<false, false, false><<<dim3(16, 4, 1), 256, 0, stream>>>(
      qln, wq, nullptr, nullptr, qproj, 1024, 256, 256, 1.f, 0, 0, 0);
  // routing scores + top-4
  k_gemm<false, false, false><<<dim3(4, 4, 4), 256, 0, stream>>>(
      qproj, imagew, nullptr, nullptr, rattn, 256, 256, 256, 0.0625f,
      65536, 65536, 65536);
  k_topk<<<256, 256, 0, stream>>>(rattn, topidx);
  // 4+5) fused gather + LN + attention (K/V projections folded)
  k_attn<<<1024, 256, 0, stream>>>(qproj, topidx, x, pos, normkv_g, normkv_b,
                                   wk, wvT, attno);
  // out = attno @ w_rec^T + query
  k_gemm<false, false, true><<<dim3(16, 4, 1), 256, 0, stream>>>(
      attno, w_rec, nullptr, query, outmid, 1024, 256, 256, 1.f, 0, 0, 0);
  // 6) residual MLP
  k_ln<<<1024, 256, 0, stream>>>(outmid, mlp_g, mlp_b, mlpln);
  k_gemm<true, true, false><<<dim3(16, 4, 1), 256, 0, stream>>>(
      mlpln, mlp_w1, mlp_b1, nullptr, h1, 1024, 256, 256, 1.f, 0, 0, 0);
  k_gemm<true, false, true><<<dim3(16, 4, 1), 256, 0, stream>>>(
      h1, mlp_w2, mlp_b2, outmid, out, 1024, 256, 256, 1.f, 0, 0, 0);
}

// Round 4
// 706.111 us; speedup vs baseline: 1.4593x; 1.0506x over previous
//
#include <hip/hip_runtime.h>
#include <math.h>

// Problem constants
// B=4, NQ=256, DQ=256, DKV=256, H_IMG=W_IMG=256, HEADS=8, DH=32,
// TOPW=4, WS=8, FACTOR=2, INNER=256, DOUT=256
// conv out spatial: 128x128 -> M=N=16 windows of 64 dilated tokens.
// x layout: [bwin(1024)][t(64)][c(256)], bwin = b*256 + m*16 + n, t = h*8+w,
// pixel (y,x) = (h*16+m, w*16+n).

typedef __bf16 bf16x8_t __attribute__((ext_vector_type(8)));
typedef float f32x4 __attribute__((ext_vector_type(4)));
typedef unsigned short ushortx8 __attribute__((ext_vector_type(8)));
typedef unsigned short ushortx4 __attribute__((ext_vector_type(4)));

__device__ __forceinline__ unsigned short f2bf(float f) {
  unsigned int u = __float_as_uint(f);
  unsigned int r = (u + 0x7FFFu + ((u >> 16) & 1u)) >> 16;   // RNE
  return (unsigned short)r;
}
__device__ __forceinline__ float bf2f(unsigned short h) {
  return __uint_as_float(((unsigned int)h) << 16);
}

#define MFMA16(a, b, c) \
  __builtin_amdgcn_mfma_f32_16x16x32_bf16( \
      __builtin_bit_cast(bf16x8_t, (a)), __builtin_bit_cast(bf16x8_t, (b)), (c), 0, 0, 0)

// ---------------- K0: pre-split conv weights to bf16 hi/lo ----------------
__global__ __launch_bounds__(256) void k_prepw(
    const float* __restrict__ cw, unsigned short* __restrict__ cwh,
    unsigned short* __restrict__ cwl)
{
  const int o = blockIdx.x;
  const int k4 = threadIdx.x * 4;
  const float4 w = *(const float4*)(cw + (size_t)o * 1024 + k4);
  float f[4] = {w.x, w.y, w.z, w.w};
  ushortx4 h, l;
#pragma unroll
  for (int i = 0; i < 4; ++i) {
    h[i] = f2bf(f[i]);
    l[i] = f2bf(f[i] - bf2f(h[i]));
  }
  *(ushortx4*)(cwh + (size_t)o * 1024 + k4) = h;
  *(ushortx4*)(cwl + (size_t)o * 1024 + k4) = l;
}

// ---------------- K1: conv patchify, split-bf16 MFMA, 64x64 wave tiles ----------------
// Block 128(M) x 128(N), 4 waves (2x2), wave tile 64x64 (4x4 16x16x32 frags),
// BK=32. 3-term split: ah*bh + al*bh + ah*bl. LDS row stride 40 ushort (80 B):
// frag reads land 2-way on banks (free); LDS read traffic halved vs 64x32 tiles.
__global__ __launch_bounds__(256) void k_conv(
    const float* __restrict__ img, const unsigned short* __restrict__ cwh,
    const unsigned short* __restrict__ cwl, const float* __restrict__ cb,
    float* __restrict__ x)
{
  __shared__ unsigned short Ah[128 * 40];
  __shared__ unsigned short Al[128 * 40];
  __shared__ unsigned short Bh[128 * 40];
  __shared__ unsigned short Bl[128 * 40];

  const int tid = threadIdx.x;
  const int blk = blockIdx.x;          // 1024 = 512 (b,y) rows x 2 n-halves
  const int nh = blk & 1, by = blk >> 1;
  const int b = by >> 7, y = by & 127;
  const int n0 = nh * 128;

  const int lane = tid & 63, wid = tid >> 6;
  const int wr = wid >> 1, wc = wid & 1;
  const int lr = lane & 15, lk = lane >> 4;

  // A staging: thread -> (row-pair r2 = tid&63, k-group g = tid>>6)
  const int r2 = tid & 63, g = tid >> 6;
  const float* abase = img + (size_t)b * 16777216 + (size_t)(2 * y) * 256 + 4 * r2;
  // B staging: thread -> (col = tid>>1, k-half kq = tid&1)
  const int bcol = tid >> 1, bkq = tid & 1;

  f32x4 acc[4][4];
#pragma unroll
  for (int i = 0; i < 4; ++i)
#pragma unroll
    for (int j = 0; j < 4; ++j) acc[i][j] = (f32x4){0.f, 0.f, 0.f, 0.f};

  for (int kc = 0; kc < 32; ++kc) {
    __syncthreads();
    // ---- stage A: rows 2*r2, 2*r2+1; k' = g*8 + cc*4 + ky*2 + kx ----
    {
      float fr0[8], fr1[8];
#pragma unroll
      for (int cc = 0; cc < 2; ++cc) {
        const int cin = kc * 8 + g * 2 + cc;
        const float* p = abase + (size_t)cin * 65536;
        const float4 v0 = *(const float4*)p;          // ky=0, pixels 4r2..4r2+3
        const float4 v1 = *(const float4*)(p + 256);  // ky=1
        fr0[cc * 4 + 0] = v0.x; fr0[cc * 4 + 1] = v0.y;
        fr0[cc * 4 + 2] = v1.x; fr0[cc * 4 + 3] = v1.y;
        fr1[cc * 4 + 0] = v0.z; fr1[cc * 4 + 1] = v0.w;
        fr1[cc * 4 + 2] = v1.z; fr1[cc * 4 + 3] = v1.w;
      }
      ushortx8 h0, l0, h1, l1;
#pragma unroll
      for (int i = 0; i < 8; ++i) {
        h0[i] = f2bf(fr0[i]); l0[i] = f2bf(fr0[i] - bf2f(h0[i]));
        h1[i] = f2bf(fr1[i]); l1[i] = f2bf(fr1[i] - bf2f(h1[i]));
      }
      *(ushortx8*)&Ah[(2 * r2 + 0) * 40 + g * 8] = h0;
      *(ushortx8*)&Al[(2 * r2 + 0) * 40 + g * 8] = l0;
      *(ushortx8*)&Ah[(2 * r2 + 1) * 40 + g * 8] = h1;
      *(ushortx8*)&Al[(2 * r2 + 1) * 40 + g * 8] = l1;
    }
    // ---- stage B: prepacked hi/lo, 2x16B per buffer per thread ----
    {
      const size_t goff = (size_t)(n0 + bcol) * 1024 + kc * 32 + bkq * 16;
      *(ushortx8*)&Bh[bcol * 40 + bkq * 16 + 0] = *(const ushortx8*)(cwh + goff);
      *(ushortx8*)&Bh[bcol * 40 + bkq * 16 + 8] = *(const ushortx8*)(cwh + goff + 8);
      *(ushortx8*)&Bl[bcol * 40 + bkq * 16 + 0] = *(const ushortx8*)(cwl + goff);
      *(ushortx8*)&Bl[bcol * 40 + bkq * 16 + 8] = *(const ushortx8*)(cwl + goff + 8);
    }
    __syncthreads();
    // ---- fragments + 3-term split MFMA ----
    ushortx8 bh4[4], bl4[4];
#pragma unroll
    for (int ni = 0; ni < 4; ++ni) {
      const int col = wc * 64 + ni * 16 + lr;
      bh4[ni] = *(ushortx8*)&Bh[col * 40 + lk * 8];
      bl4[ni] = *(ushortx8*)&Bl[col * 40 + lk * 8];
    }
#pragma unroll
    for (int mi = 0; mi < 4; ++mi) {
      const int row = wr * 64 + mi * 16 + lr;
      const ushortx8 ah = *(ushortx8*)&Ah[row * 40 + lk * 8];
      const ushortx8 al = *(ushortx8*)&Al[row * 40 + lk * 8];
#pragma unroll
      for (int ni = 0; ni < 4; ++ni) {
        acc[mi][ni] = MFMA16(ah, bh4[ni], acc[mi][ni]);
        acc[mi][ni] = MFMA16(al, bh4[ni], acc[mi][ni]);
        acc[mi][ni] = MFMA16(ah, bl4[ni], acc[mi][ni]);
      }
    }
  }
  // ---- epilogue: + bias, scatter into dilated-window layout ----
  const int hh = y >> 4, mm = y & 15;
#pragma unroll
  for (int mi = 0; mi < 4; ++mi) {
    const int pbase = wr * 64 + mi * 16 + lk * 4;
#pragma unroll
    for (int ni = 0; ni < 4; ++ni) {
      const int c = n0 + wc * 64 + ni * 16 + lr;
      const float cbv = cb[c];
#pragma unroll
      for (int r = 0; r < 4; ++r) {
        const int p = pbase + r;
        const int w = p >> 4, n = p & 15;
        const int bwin = b * 256 + mm * 16 + n;
        const int t = hh * 8 + w;
        x[(size_t)(bwin * 64 + t) * 256 + c] = acc[mi][ni][r] + cbv;
      }
    }
  }
}

// ---------------- K2: double softmax_one window pooling (wave-parallel) ----------------
__global__ __launch_bounds__(256) void k_winpool(
    const float* __restrict__ x, float* __restrict__ imagew)
{
  __shared__ float Xs[64][132];     // half of channels at a time
  __shared__ float cor[64][65];
  __shared__ float part[4][64];
  __shared__ float wgt[64];
  const int bwin = blockIdx.x;
  const int tid = threadIdx.x;
  const int ty = tid >> 4, tx = tid & 15;
  const float* xw = x + (size_t)bwin * 16384;

  float acc[4][4];
#pragma unroll
  for (int i = 0; i < 4; ++i)
#pragma unroll
    for (int j = 0; j < 4; ++j) acc[i][j] = 0.f;

  for (int half = 0; half < 2; ++half) {
    {
      const int t = tid >> 2, c4 = tid & 3;
      const float* src = xw + t * 256 + half * 128;
#pragma unroll
      for (int i = 0; i < 8; ++i) {
        const int chunk = c4 + 4 * i;
        *(float4*)&Xs[t][chunk * 4] = *(const float4*)(src + chunk * 4);
      }
    }
    __syncthreads();
    for (int c = 0; c < 128; c += 4) {
      float4 av[4], bv[4];
#pragma unroll
      for (int i = 0; i < 4; ++i) av[i] = *(const float4*)&Xs[ty + 16 * i][c];
#pragma unroll
      for (int j = 0; j < 4; ++j) bv[j] = *(const float4*)&Xs[tx + 16 * j][c];
#pragma unroll
      for (int i = 0; i < 4; ++i)
#pragma unroll
        for (int j = 0; j < 4; ++j)
          acc[i][j] += av[i].x * bv[j].x + av[i].y * bv[j].y +
                       av[i].z * bv[j].z + av[i].w * bv[j].w;
    }
    __syncthreads();
  }
  const float sc = 0.0625f;   // DKV^-0.5
#pragma unroll
  for (int i = 0; i < 4; ++i)
#pragma unroll
    for (int j = 0; j < 4; ++j) cor[ty + 16 * i][tx + 16 * j] = acc[i][j] * sc;
  __syncthreads();
  // row softmax_one over q: thread = (p = tid&63, q-quarter = tid>>6)
  const int p = tid & 63, q4 = tid >> 6;
  {
    float m = -INFINITY;
#pragma unroll
    for (int i = 0; i < 16; ++i) m = fmaxf(m, cor[p][q4 * 16 + i]);
    part[q4][p] = m;
  }
  __syncthreads();
  {
    const float M = fmaxf(fmaxf(part[0][p], part[1][p]),
                          fmaxf(part[2][p], part[3][p]));
    float s = 0.f;
#pragma unroll
    for (int i = 0; i < 16; ++i) {
      const float e = expf(cor[p][q4 * 16 + i] - M);
      cor[p][q4 * 16 + i] = e; s += e;
    }
    __syncthreads();                 // everyone done reading part (max)
    part[q4][p] = s;
  }
  __syncthreads();
  {
    const float S = part[0][p] + part[1][p] + part[2][p] + part[3][p];
    const float inv = 1.f / (1.f + S);
#pragma unroll
    for (int i = 0; i < 16; ++i) cor[p][q4 * 16 + i] *= inv;
  }
  __syncthreads();
  // column sums over p: thread = (q = tid&63, p-quarter = tid>>6)
  {
    const int q = tid & 63, p4 = tid >> 6;
    float s = 0.f;
#pragma unroll
    for (int i = 0; i < 16; ++i) s += cor[p4 * 16 + i][q];
    part[p4][q] = s;
  }
  __syncthreads();
  if (tid < 64) {
    const int qq = tid;
    float s = part[0][qq] + part[1][qq] + part[2][qq] + part[3][qq];
    float m = s;
#pragma unroll
    for (int o = 1; o < 64; o <<= 1) m = fmaxf(m, __shfl_xor(m, o));
    const float e = expf(s - m);
    float tsum = e;
#pragma unroll
    for (int o = 1; o < 64; o <<= 1) tsum += __shfl_xor(tsum, o);
    wgt[qq] = e / (1.f + tsum);
  }
  __syncthreads();
  // imagew[c] = sum_q wgt[q] * x[q][c]  (x re-read from global, L2-hot)
  {
    const int c = tid;
    float a = 0.f;
    for (int qq = 0; qq < 64; ++qq) a += wgt[qq] * xw[qq * 256 + c];
    imagew[(size_t)bwin * 256 + c] = a;
  }
}

// ---------------- K3: row LayerNorm (rows of 256) ----------------
__global__ __launch_bounds__(256) void k_ln(
    const float* __restrict__ in, const float* __restrict__ g,
    const float* __restrict__ bb, float* __restrict__ out)
{
  const int row = blockIdx.x, tid = threadIdx.x;
  const float v = in[(size_t)row * 256 + tid];
  float s = v, s2 = v * v;
#pragma unroll
  for (int o = 1; o < 64; o <<= 1) { s += __shfl_xor(s, o); s2 += __shfl_xor(s2, o); }
  __shared__ float ps[4], ps2[4];
  if ((tid & 63) == 0) { ps[tid >> 6] = s; ps2[tid >> 6] = s2; }
  __syncthreads();
  const float S = ps[0] + ps[1] + ps[2] + ps[3];
  const float S2 = ps2[0] + ps2[1] + ps2[2] + ps2[3];
  const float mu = S * (1.f / 256.f);
  const float rs = rsqrtf(S2 * (1.f / 256.f) - mu * mu + 1e-5f);
  out[(size_t)row * 256 + tid] = (v - mu) * rs * g[tid] + bb[tid];
}

// ---------------- K4: tiled GEMM 32x64  C = act(A @ B^T * scale + bias) + res ----------------
template <bool BIAS, bool RELU, bool RES>
__global__ __launch_bounds__(256) void k_gemm(
    const float* __restrict__ A, const float* __restrict__ B,
    const float* __restrict__ bias, const float* __restrict__ res,
    float* __restrict__ C, int M, int N, int K, float scale,
    long aZ, long bZ, long cZ)
{
  A += (size_t)blockIdx.z * aZ;
  B += (size_t)blockIdx.z * bZ;
  C += (size_t)blockIdx.z * cZ;
  const float* R = RES ? res + (size_t)blockIdx.z * cZ : nullptr;
  __shared__ float As[32][33], Bs[32][65];   // k-major
  const int m0 = blockIdx.x * 32, n0 = blockIdx.y * 64;
  const int tid = threadIdx.x;
  const int ty = tid >> 4, tx = tid & 15;
  const int ar = tid >> 3, ag = tid & 7;
  const int br = tid >> 2, bg = tid & 3;
  float acc[2][4];
#pragma unroll
  for (int i = 0; i < 2; ++i)
#pragma unroll
    for (int j = 0; j < 4; ++j) acc[i][j] = 0.f;

  for (int kc = 0; kc < K; kc += 32) {
    {
      const float4 va = *(const float4*)(A + (size_t)(m0 + ar) * K + kc + ag * 4);
      As[ag * 4 + 0][ar] = va.x; As[ag * 4 + 1][ar] = va.y;
      As[ag * 4 + 2][ar] = va.z; As[ag * 4 + 3][ar] = va.w;
      const float4 vb0 = *(const float4*)(B + (size_t)(n0 + br) * K + kc + bg * 8);
      const float4 vb1 = *(const float4*)(B + (size_t)(n0 + br) * K + kc + bg * 8 + 4);
      Bs[bg * 8 + 0][br] = vb0.x; Bs[bg * 8 + 1][br] = vb0.y;
      Bs[bg * 8 + 2][br] = vb0.z; Bs[bg * 8 + 3][br] = vb0.w;
      Bs[bg * 8 + 4][br] = vb1.x; Bs[bg * 8 + 5][br] = vb1.y;
      Bs[bg * 8 + 6][br] = vb1.z; Bs[bg * 8 + 7][br] = vb1.w;
    }
    __syncthreads();
#pragma unroll
    for (int kk = 0; kk < 32; ++kk) {
      float a[2], bb2[4];
#pragma unroll
      for (int i = 0; i < 2; ++i) a[i] = As[kk][ty + 16 * i];
#pragma unroll
      for (int j = 0; j < 4; ++j) bb2[j] = Bs[kk][tx + 16 * j];
#pragma unroll
      for (int i = 0; i < 2; ++i)
#pragma unroll
        for (int j = 0; j < 4; ++j) acc[i][j] += a[i] * bb2[j];
    }
    __syncthreads();
  }
#pragma unroll
  for (int i = 0; i < 2; ++i) {
    const int mi = m0 + ty + 16 * i;
#pragma unroll
    for (int j = 0; j < 4; ++j) {
      const int nj = n0 + tx + 16 * j;
      float v = acc[i][j] * scale;
      if (BIAS) v += bias[nj];
      if (RELU) v = fmaxf(v, 0.f);
      if (RES) v += R[(size_t)mi * N + nj];
      C[(size_t)mi * N + nj] = v;
    }
  }
}

// ---------------- K5: top-4 window routing (matches lax.top_k tie-break) ----------------
__global__ __launch_bounds__(256) void k_topk(
    const float* __restrict__ rattn, int* __restrict__ outi)
{
  const int pair = blockIdx.x * 4 + (threadIdx.x >> 6);   // (b*256+q)
  const int lane = threadIdx.x & 63;
  const float* rp = rattn + (size_t)pair * 256;
  float v[4];
#pragma unroll
  for (int i = 0; i < 4; ++i) v[i] = rp[i * 64 + lane];
  int selmask = 0;
  for (int rsel = 0; rsel < 4; ++rsel) {
    float bv = -INFINITY; int bi = 1 << 30;
#pragma unroll
    for (int i = 0; i < 4; ++i) {
      if (!(selmask & (1 << i))) {
        const float val = v[i]; const int idx = i * 64 + lane;
        if (val > bv || (val == bv && idx < bi)) { bv = val; bi = idx; }
      }
    }
#pragma unroll
    for (int o = 1; o < 64; o <<= 1) {
      const float ov = __shfl_xor(bv, o); const int oi = __shfl_xor(bi, o);
      if (ov > bv || (ov == bv && oi < bi)) { bv = ov; bi = oi; }
    }
    if (lane == 0) outi[pair * 4 + rsel] = bi;
    if (lane == (bi & 63)) selmask |= 1 << (bi >> 6);
  }
}

// ---------------- K6: fused gather + LN-folded attention per (b,q) ----------------
__global__ __launch_bounds__(256) void k_attn(
    const float* __restrict__ qp, const int* __restrict__ topidx,
    const float* __restrict__ x, const float* __restrict__ pos,
    const float* __restrict__ nkg, const float* __restrict__ nkb,
    const float* __restrict__ wk, const float* __restrict__ wvT,
    float* __restrict__ attnout)
{
  __shared__ float qrow[256];
  __shared__ float qWg[8][260];       // chunk-swizzled (see qwg offset)
  __shared__ float Raw[32][260];
  __shared__ float pooled[8][256];
  __shared__ float dts[8][32];
  __shared__ float muT[32], rsT[32];
  __shared__ float Gh[8], qWb[8], mh[8], lh[8], S1[8], scl[8];

  const int bq = blockIdx.x;
  const int b = bq >> 8;
  const int tid = threadIdx.x;

  qrow[tid] = qp[(size_t)bq * 256 + tid];
#pragma unroll
  for (int h = 0; h < 8; ++h) pooled[h][tid] = 0.f;
  if (tid < 8) { Gh[tid] = 0.f; qWb[tid] = 0.f; mh[tid] = -INFINITY; lh[tid] = 0.f; S1[tid] = 0.f; }
  __syncthreads();

  // per-head folded query: qWg[h][c] = (sum_j q[h*32+j] wk[h*32+j][c]) * DH^-0.5 * g[c]
  {
    const float qs = 0.17677669529663689f;  // 1/sqrt(32)
    const float gc = nkg[tid], bc = nkb[tid];
    const int ch = tid >> 2, lo = tid & 3;
    const int off = (((ch & 7) << 3) | (ch >> 3)) * 4 + lo;   // 3-3 bit-swap chunk swizzle
#pragma unroll
    for (int h = 0; h < 8; ++h) {
      float a = 0.f;
#pragma unroll
      for (int j = 0; j < 32; ++j)
        a += qrow[h * 32 + j] * wk[(size_t)(h * 32 + j) * 256 + tid];
      a *= qs;
      qWg[h][off] = a * gc;
      float v1 = a * gc, v2 = a * bc;
#pragma unroll
      for (int o = 1; o < 64; o <<= 1) { v1 += __shfl_xor(v1, o); v2 += __shfl_xor(v2, o); }
      if ((tid & 63) == 0) { atomicAdd(&Gh[h], v1); atomicAdd(&qWb[h], v2); }
    }
  }
  __syncthreads();

  for (int tile = 0; tile < 8; ++tile) {          // 4 windows x 2 half-tiles of 32 tokens
    const int w = tile >> 1, th = tile & 1;
    const int win = topidx[bq * 4 + w];
    // stage raw = x + pos, with per-token stats
    {
      const int tt = tid >> 3, c8 = tid & 7;
      const float* xs = x + ((size_t)(b * 256 + win) * 64 + th * 32 + tt) * 256;
      const float* ps = pos + (size_t)(w * 64 + th * 32 + tt) * 256;
      float s = 0.f, s2 = 0.f;
#pragma unroll
      for (int i = 0; i < 8; ++i) {
        const int ck = c8 + 8 * i;
        float4 v = *(const float4*)(xs + ck * 4);
        const float4 p4 = *(const float4*)(ps + ck * 4);
        v.x += p4.x; v.y += p4.y; v.z += p4.z; v.w += p4.w;
        *(float4*)&Raw[tt][ck * 4] = v;
        s += v.x + v.y + v.z + v.w;
        s2 += v.x * v.x + v.y * v.y + v.z * v.z + v.w * v.w;
      }
#pragma unroll
      for (int o = 1; o < 8; o <<= 1) { s += __shfl_xor(s, o); s2 += __shfl_xor(s2, o); }
      if (c8 == 0) {
        const float mu = s * (1.f / 256.f);
        muT[tt] = mu;
        rsT[tt] = rsqrtf(s2 * (1.f / 256.f) - mu * mu + 1e-5f);
      }
    }
    __syncthreads();
    // dots for 8 heads x 32 tokens; each thread = (token, c-slice of 32)
    {
      const int tt = tid >> 3, cq = tid & 7;
      float ds[8];
#pragma unroll
      for (int h = 0; h < 8; ++h) ds[h] = 0.f;
#pragma unroll
      for (int ch = 0; ch < 8; ++ch) {
        const float4 rv = *(const float4*)&Raw[tt][cq * 32 + ch * 4];
#pragma unroll
        for (int h = 0; h < 8; ++h) {
          const float4 qv = *(const float4*)&qWg[h][32 * ch + 4 * cq];
          ds[h] += rv.x * qv.x + rv.y * qv.y + rv.z * qv.z + rv.w * qv.w;
        }
      }
#pragma unroll
      for (int o = 1; o < 8; o <<= 1)
#pragma unroll
        for (int h = 0; h < 8; ++h) ds[h] += __shfl_xor(ds[h], o);
      if (cq == 0) {
        const float rs = rsT[tt], mu = muT[tt];
#pragma unroll
        for (int h = 0; h < 8; ++h)
          dts[h][tt] = rs * ds[h] - rs * mu * Gh[h] + qWb[h];
      }
    }
    __syncthreads();
    // online softmax update per head
    {
      const int h = tid >> 5, tt = tid & 31;
      const float d = dts[h][tt];
      float tm = d;
#pragma unroll
      for (int o = 1; o < 32; o <<= 1) tm = fmaxf(tm, __shfl_xor(tm, o));
      const float mold = mh[h];
      const float mnew = fmaxf(mold, tm);
      const float e = expf(d - mnew);
      const float wE = e * rsT[tt];
      dts[h][tt] = wE;                 // weight for pooled accumulation
      float s1 = e, s2 = wE * muT[tt];
#pragma unroll
      for (int o = 1; o < 32; o <<= 1) { s1 += __shfl_xor(s1, o); s2 += __shfl_xor(s2, o); }
      if (tt == 0) {
        const float f = expf(mold - mnew);
        lh[h] = lh[h] * f + s1;
        S1[h] = S1[h] * f + s2;
        mh[h] = mnew;
        scl[h] = f;
      }
    }
    __syncthreads();
    // pooled[h][c] = pooled*f + sum_t wE[t]*raw[t][c]
    {
      const int h = tid >> 5, cg = tid & 31;
      const float f = scl[h];
#pragma unroll
      for (int rep = 0; rep < 2; ++rep) {
        const int c = cg * 4 + rep * 128;
        float4 p = *(const float4*)&pooled[h][c];
        p.x *= f; p.y *= f; p.z *= f; p.w *= f;
#pragma unroll 8
        for (int t2 = 0; t2 < 32; ++t2) {
          const float wE = dts[h][t2];
          const float4 rv = *(const float4*)&Raw[t2][c];
          p.x += wE * rv.x; p.y += wE * rv.y; p.z += wE * rv.z; p.w += wE * rv.w;
        }
        *(float4*)&pooled[h][c] = p;
      }
    }
    __syncthreads();
  }
  // finalize: pf = g*(praw - S1)/l + b  (softmax sums to 1)
  {
    const int h = tid >> 5, cg = tid & 31;
    const float linv = 1.f / lh[h];
    const float s1v = S1[h];
#pragma unroll
    for (int rep = 0; rep < 8; ++rep) {
      const int c = cg + rep * 32;
      pooled[h][c] = nkg[c] * (pooled[h][c] - s1v) * linv + nkb[c];
    }
  }
  __syncthreads();
  // attnout[j] = sum_c pf[h(j)][c] * wv[j][c]   (wvT is wv transposed)
  {
    const int j = tid, h = j >> 5;
    float a = 0.f;
    for (int c = 0; c < 256; ++c)
      a += pooled[h][c] * wvT[(size_t)c * 256 + j];
    attnout[(size_t)bq * 256 + j] = a;
  }
}

// ---------------- K7: 256x256 transpose (wv -> wvT) ----------------
__global__ void k_transpose256(const float* __restrict__ in, float* __restrict__ out)
{
  __shared__ float tile[32][33];
  const int bx = blockIdx.x * 32, by = blockIdx.y * 32;
  const int tx = threadIdx.x, ty = threadIdx.y;
#pragma unroll
  for (int i = 0; i < 32; i += 8)
    tile[ty + i][tx] = in[(size_t)(by + ty + i) * 256 + bx + tx];
  __syncthreads();
#pragma unroll
  for (int i = 0; i < 32; i += 8)
    out[(size_t)(bx + ty + i) * 256 + by + tx] = tile[tx][ty + i];
}

// ---------------- launch ----------------
extern "C" void kernel_launch(void* const* d_in, const int* in_sizes, int n_in,
                              void* d_out, int out_size, void* d_ws, size_t ws_size,
                              hipStream_t stream)
{
  const float* query   = (const float*)d_in[0];
  const float* image   = (const float*)d_in[1];
  const float* conv_w  = (const float*)d_in[2];
  const float* conv_b  = (const float*)d_in[3];
  const float* pos     = (const float*)d_in[4];
  const float* normq_g = (const float*)d_in[5];
  const float* normq_b = (const float*)d_in[6];
  const float* normkv_g= (const float*)d_in[7];
  const float* normkv_b= (const float*)d_in[8];
  const float* wq      = (const float*)d_in[9];
  const float* wk      = (const float*)d_in[10];
  const float* wv      = (const float*)d_in[11];
  const float* w_rec   = (const float*)d_in[12];
  const float* mlp_g   = (const float*)d_in[13];
  const float* mlp_b   = (const float*)d_in[14];
  const float* mlp_w1  = (const float*)d_in[15];
  const float* mlp_b1  = (const float*)d_in[16];
  const float* mlp_w2  = (const float*)d_in[17];
  const float* mlp_b2  = (const float*)d_in[18];
  float* out = (float*)d_out;

  float* ws = (float*)d_ws;
  float* x      = ws;                    // 16,777,216 f
  float* imagew = x + 16777216;          // 262,144 f
  float* qln    = imagew + 262144;
  float* qproj  = qln + 262144;
  float* rattn  = qproj + 262144;
  float* attno  = rattn + 262144;
  float* outmid = attno + 262144;
  float* mlpln  = outmid + 262144;
  float* h1     = mlpln + 262144;
  float* wvT    = h1 + 262144;           // 65,536 f
  int*   topidx = (int*)(wvT + 65536);   // 4,096 i32
  // conv weight hi/lo aliased onto rattn (1 MB): consumed by k_conv before
  // rattn is written by the routing GEMM (stream-ordered, no overlap in time)
  unsigned short* cwh = (unsigned short*)rattn;   // 262,144 bf16 (512 KB)
  unsigned short* cwl = cwh + 262144;             // 262,144 bf16 (512 KB)

  // 0) split conv weights to bf16 hi/lo
  k_prepw<<<256, 256, 0, stream>>>(conv_w, cwh, cwl);
  // 1) conv patchify -> x (windowed layout), split-bf16 MFMA
  k_conv<<<1024, 256, 0, stream>>>(image, cwh, cwl, conv_b, x);
  // prep: transpose wv for coalesced epilogue reads
  k_transpose256<<<dim3(8, 8), dim3(32, 8), 0, stream>>>(wv, wvT);
  // 2) window pooling -> imagew
  k_winpool<<<1024, 256, 0, stream>>>(x, imagew);
  // 3) q = LN(query) @ wq^T
  k_ln<<<1024, 256, 0, stream>>>(query, normq_g, normq_b, qln);
  k_gemm<false, false, false><<<dim3(32, 4, 1), 256, 0, stream>>>(
      qln, wq, nullptr, nullptr, qproj, 1024, 256, 256, 1.f, 0, 0, 0);
  // routing scores + top-4
  k_gemm<false, false, false><<<dim3(8, 4, 4), 256, 0, stream>>>(
      qproj, imagew, nullptr, nullptr, rattn, 256, 256, 256, 0.0625f,
      65536, 65536, 65536);
  k_topk<<<256, 256, 0, stream>>>(rattn, topidx);
  // 4+5) fused gather + LN + attention (K/V projections folded)
  k_attn<<<1024, 256, 0, stream>>>(qproj, topidx, x, pos, normkv_g, normkv_b,
                                   wk, wvT, attno);
  // out = attno @ w_rec^T + query
  k_gemm<false, false, true><<<dim3(32, 4, 1), 256, 0, stream>>>(
      attno, w_rec, nullptr, query, outmid, 1024, 256, 256, 1.f, 0, 0, 0);
  // 6) residual MLP
  k_ln<<<1024, 256, 0, stream>>>(outmid, mlp_g, mlp_b, mlpln);
  k_gemm<true, true, false><<<dim3(32, 4, 1), 256, 0, stream>>>(
      mlpln, mlp_w1, mlp_b1, nullptr, h1, 1024, 256, 256, 1.f, 0, 0, 0);
  k_gemm<true, false, true><<<dim3(32, 4, 1), 256, 0, stream>>>(
      h1, mlp_w2, mlp_b2, outmid, out, 1024, 256, 256, 1.f, 0, 0, 0);
}